// Round 16
// baseline (370.731 us; speedup 1.0000x reference)
//
#include <hip/hip_runtime.h>

typedef __bf16 bf16x8 __attribute__((ext_vector_type(8)));
typedef float f32x4 __attribute__((ext_vector_type(4)));
typedef unsigned short u16x8 __attribute__((ext_vector_type(8)));
typedef unsigned short u16x4 __attribute__((ext_vector_type(4)));
typedef unsigned short u16x2 __attribute__((ext_vector_type(2)));

__device__ inline unsigned short f2bf(float f) {
    return __builtin_bit_cast(unsigned short, (__bf16)f);
}
__device__ inline float bf2f(unsigned short u) {
    return (float)__builtin_bit_cast(__bf16, u);
}

// native 2^x (v_exp_f32 is exp2 on gfx950); avoids libm header clash
__device__ __forceinline__ float fexp2(float x) {
    float r;
    asm("v_exp_f32 %0, %1" : "=v"(r) : "v"(x));
    return r;
}

__device__ inline void storeC(float v, float* p) { *p = v; }
__device__ inline void storeC(float v, unsigned short* p) { *p = f2bf(v); }

#define MFMA16(a, b, c) __builtin_amdgcn_mfma_f32_16x16x32_bf16( \
    __builtin_bit_cast(bf16x8, a), __builtin_bit_cast(bf16x8, b), (c), 0, 0, 0)

// async global->LDS, 16B per lane; LDS dest = wave-uniform base + lane*16
__device__ inline void gload16(const unsigned short* g, unsigned short* l) {
    __builtin_amdgcn_global_load_lds(
        (const __attribute__((address_space(1))) unsigned int*)(g),
        (__attribute__((address_space(3))) unsigned int*)(l), 16, 0, 0);
}

__device__ __forceinline__ void bar() {
    asm volatile("" ::: "memory");
    __builtin_amdgcn_s_barrier();
    asm volatile("" ::: "memory");
}
#define WAITVM(N) asm volatile("s_waitcnt vmcnt(" #N ")" ::: "memory")

// ---------------------------------------------------------------------------
// Merged prep (R15-proven): convert + 4 weight transposes, one dispatch.
// 128x128 transpose tiles, LDS stride 130 (conflict-free), output swizzled
// per GEMM contract: within each 64-hw k-block, 8-slot ^= (n&7).
// ---------------------------------------------------------------------------
__device__ void transpose_tile128(const float* __restrict__ W,
                                  unsigned short* __restrict__ WT,
                                  int K, int N, int bx, int by,
                                  unsigned short* t_lds)
{
    constexpr int LDT = 130;
    const int kt = bx * 128, nt = by * 128;
    const int tid = threadIdx.x;
    const int c = (tid & 31) * 4;
    const int r0 = tid >> 5;
    #pragma unroll
    for (int p = 0; p < 16; ++p) {
        const int r = p * 8 + r0;
        float4 v = *(const float4*)&W[(size_t)(kt + r) * N + nt + c];
        u16x4 h;
        h[0] = f2bf(v.x); h[1] = f2bf(v.y); h[2] = f2bf(v.z); h[3] = f2bf(v.w);
        *(u16x4*)&t_lds[r * LDT + c] = h;
    }
    __syncthreads();
    const int kc = (tid >> 4) * 8;
    const int n0 = tid & 15;
    #pragma unroll
    for (int p = 0; p < 8; ++p) {
        const int n = p * 16 + n0;
        u16x8 o;
        #pragma unroll
        for (int j = 0; j < 8; ++j)
            o[j] = t_lds[(kc + j) * LDT + n];
        const int swz = (kc & 64) | ((kc & 63) ^ ((n & 7) << 3));
        *(u16x8*)&WT[(size_t)(nt + n) * K + kt + swz] = o;
    }
}

__global__ __launch_bounds__(256) void prep_all(
    const float* __restrict__ hidden, const float* __restrict__ wq,
    const float* __restrict__ wk, const float* __restrict__ wv,
    const float* __restrict__ wo, unsigned short* __restrict__ hb,
    unsigned short* __restrict__ wqt, unsigned short* __restrict__ wkt,
    unsigned short* __restrict__ wot)
{
    __shared__ __attribute__((aligned(16))) unsigned short t_lds[128 * 130];
    const int bid = blockIdx.x;
    if (bid < 4096) {
        const size_t i = ((size_t)bid * 256 + threadIdx.x) * 8;
        const size_t row7 = (i >> 12) & 7;
        float4 v0 = *(const float4*)&hidden[i];
        float4 v1 = *(const float4*)&hidden[i + 4];
        u16x8 o;
        o[0] = f2bf(v0.x); o[1] = f2bf(v0.y); o[2] = f2bf(v0.z); o[3] = f2bf(v0.w);
        o[4] = f2bf(v1.x); o[5] = f2bf(v1.y); o[6] = f2bf(v1.z); o[7] = f2bf(v1.w);
        *(u16x8*)&hb[i ^ (row7 << 3)] = o;
    } else if (bid < 5120) {
        const int tb = bid - 4096;
        transpose_tile128(wq, wqt, 4096, 4096, tb & 31, tb >> 5, t_lds);
    } else if (bid < 5376) {
        const int tb = bid - 5120;
        transpose_tile128(wk, wkt, 4096, 1024, tb & 31, tb >> 5, t_lds);
    } else if (bid < 5632) {
        const int tb = bid - 5376;
        transpose_tile128(wv, wkt + (size_t)1024 * 4096, 4096, 1024,
                          tb & 31, tb >> 5, t_lds);
    } else {
        const int tb = bid - 5632;
        transpose_tile128(wo, wot, 4096, 4096, tb & 31, tb >> 5, t_lds);
    }
}

// ---------------------------------------------------------------------------
// 256x256 K-split GEMM (T-stack tile rung): P[z] = A[.,kz] * B[.,kz]^T,
// A/B bf16 K-major (global stride 4096), sources pre-swizzled.
// 8 waves (2Mx4N), wave output 128x64 -> 0.375 ds_reads/MFMA (vs 0.5 at
// 64x64). DOUBLE-buffered LDS (128 KB, 1 block/CU, 2 waves/SIMD).
// R11-proven rhythm: phase A {12 reads + all 8 DMA rounds of t+1; bar;
// 32 MFMA}, phase B {12 reads; vmcnt(0) (loads have ~phase-A cover); bar;
// 32 MFMA}; end bar. Dbuf hazard: buffer staged in phase A of t was last
// read in tile t-1, all reads retired behind two barriers.
// K = per-z length; kbase = z*K; partials at P + z*M*N (f32).
// ---------------------------------------------------------------------------
__global__ __launch_bounds__(512, 2) void gemm256(
    const unsigned short* __restrict__ A, const unsigned short* __restrict__ B,
    float* __restrict__ P, int M, int N, int K)
{
    constexpr int TSZ = 256 * 64;
    __shared__ __attribute__((aligned(16))) unsigned short a_lds[2 * TSZ];
    __shared__ __attribute__((aligned(16))) unsigned short b_lds[2 * TSZ];

    const int bm0 = blockIdx.y * 256, bn0 = blockIdx.x * 256;
    const int tid = threadIdx.x, lane = tid & 63, wid = tid >> 6;
    const int wr = wid >> 2, wc = wid & 3;
    const int l15 = lane & 15, koff = (lane >> 4) * 8;
    const int sw = (l15 & 7) << 3;
    const int cb0 = koff ^ sw, cb1 = (32 + koff) ^ sw;

    f32x4 acc[8][4] = {};

    const size_t kbase = (size_t)blockIdx.z * K;
    const int r8 = tid >> 3, c8 = (tid & 7) * 8;
    const unsigned short* ag = A + (size_t)(bm0 + r8) * 4096 + c8 + kbase;
    const unsigned short* bg = B + (size_t)(bn0 + r8) * 4096 + c8 + kbase;

    auto stage = [&](int bf, int kt) {
        unsigned short* ab = a_lds + bf * TSZ;
        unsigned short* bb = b_lds + bf * TSZ;
        #pragma unroll
        for (int p = 0; p < 4; ++p)
            gload16(ag + (size_t)(p * 64) * 4096 + kt, ab + p * 4096 + wid * 512);
        #pragma unroll
        for (int p = 0; p < 4; ++p)
            gload16(bg + (size_t)(p * 64) * 4096 + kt, bb + p * 4096 + wid * 512);
    };

    const int nt = K >> 6;
    stage(0, 0);
    WAITVM(0);
    bar();

    for (int t = 0; t < nt; ++t) {
        const int buf = t & 1;
        const unsigned short* ab = a_lds + buf * TSZ;
        const unsigned short* bb = b_lds + buf * TSZ;
        u16x8 af[8], bf4[4];

        // ---- Phase A: kk0 reads + all 8 DMA rounds for t+1, then 32 MFMA
        #pragma unroll
        for (int i = 0; i < 8; ++i)
            af[i] = *(const u16x8*)&ab[(wr * 128 + i * 16 + l15) * 64 + cb0];
        #pragma unroll
        for (int j = 0; j < 4; ++j)
            bf4[j] = *(const u16x8*)&bb[(wc * 64 + j * 16 + l15) * 64 + cb0];
        if (t + 1 < nt) stage(buf ^ 1, (t + 1) << 6);
        bar();
        __builtin_amdgcn_s_setprio(1);
        #pragma unroll
        for (int i = 0; i < 8; ++i)
            #pragma unroll
            for (int j = 0; j < 4; ++j)
                acc[i][j] = MFMA16(af[i], bf4[j], acc[i][j]);
        __builtin_amdgcn_s_setprio(0);

        // ---- Phase B: kk1 reads; publish t+1 (vmcnt0 + bar); 32 MFMA
        #pragma unroll
        for (int i = 0; i < 8; ++i)
            af[i] = *(const u16x8*)&ab[(wr * 128 + i * 16 + l15) * 64 + cb1];
        #pragma unroll
        for (int j = 0; j < 4; ++j)
            bf4[j] = *(const u16x8*)&bb[(wc * 64 + j * 16 + l15) * 64 + cb1];
        WAITVM(0);
        bar();
        __builtin_amdgcn_s_setprio(1);
        #pragma unroll
        for (int i = 0; i < 8; ++i)
            #pragma unroll
            for (int j = 0; j < 4; ++j)
                acc[i][j] = MFMA16(af[i], bf4[j], acc[i][j]);
        __builtin_amdgcn_s_setprio(0);

        bar();              // end of tile: all reads of buf complete
    }

    float* Pz = P + (size_t)blockIdx.z * M * N;
    #pragma unroll
    for (int i = 0; i < 8; ++i)
        #pragma unroll
        for (int r = 0; r < 4; ++r) {
            const int row = bm0 + wr * 128 + i * 16 + (lane >> 4) * 4 + r;
            size_t base = (size_t)row * N + bn0 + wc * 64 + l15;
            #pragma unroll
            for (int j = 0; j < 4; ++j)
                Pz[base + j * 16] = acc[i][j][r];
        }
}

// ---------------------------------------------------------------------------
// combine2_bf16: Y = bf16(P0 + P1), n elems per partial (8 elems/thread)
// combine2_f32 : Y = P0 + P1 (4 elems/thread)
// ---------------------------------------------------------------------------
__global__ __launch_bounds__(256) void combine2_bf16(
    const float* __restrict__ P, unsigned short* __restrict__ Y, size_t n)
{
    const size_t i = ((size_t)blockIdx.x * 256 + threadIdx.x) * 8;
    const float* P1 = P + n;
    u16x8 o;
    #pragma unroll
    for (int j = 0; j < 8; j += 4) {
        float4 a = *(const float4*)&P[i + j];
        float4 b = *(const float4*)&P1[i + j];
        o[j + 0] = f2bf(a.x + b.x); o[j + 1] = f2bf(a.y + b.y);
        o[j + 2] = f2bf(a.z + b.z); o[j + 3] = f2bf(a.w + b.w);
    }
    *(u16x8*)&Y[i] = o;
}

__global__ __launch_bounds__(256) void combine2_f32(
    const float* __restrict__ P, float* __restrict__ Y, size_t n)
{
    const size_t i = ((size_t)blockIdx.x * 256 + threadIdx.x) * 4;
    float4 a = *(const float4*)&P[i];
    float4 b = *(const float4*)&P[i + n];
    float4 o;
    o.x = a.x + b.x; o.y = a.y + b.y; o.z = a.z + b.z; o.w = a.w + b.w;
    *(float4*)&Y[i] = o;
}

// ---------------------------------------------------------------------------
// combine_kv4: sum 4 K-split partials (f32 [4][2048][2048]) ->
//   cols <1024  : k_ws bf16 [2048][1024] (direct)
//   cols >=1024 : vt_ws bf16 [1024][2048] (transposed via LDS)
// ---------------------------------------------------------------------------
__global__ __launch_bounds__(256) void combine_kv4(
    const float* __restrict__ P, unsigned short* __restrict__ Kout,
    unsigned short* __restrict__ VTout)
{
    const int s0 = blockIdx.y * 64, c0 = blockIdx.x * 64;
    const int tid = threadIdx.x;
    const int row = tid >> 2;
    const int cbl = (tid & 3) * 16;
    const size_t gbase = (size_t)(s0 + row) * 2048 + c0 + cbl;
    const size_t zs = (size_t)2048 * 2048;
    u16x8 o[2];
    #pragma unroll
    for (int j = 0; j < 2; ++j) {
        float s[8] = {};
        #pragma unroll
        for (int z = 0; z < 4; ++z) {
            float4 a = *(const float4*)&P[z * zs + gbase + j * 8];
            float4 b = *(const float4*)&P[z * zs + gbase + j * 8 + 4];
            s[0] += a.x; s[1] += a.y; s[2] += a.z; s[3] += a.w;
            s[4] += b.x; s[5] += b.y; s[6] += b.z; s[7] += b.w;
        }
        #pragma unroll
        for (int e = 0; e < 8; ++e) o[j][e] = f2bf(s[e]);
    }
    if (c0 < 1024) {
        #pragma unroll
        for (int j = 0; j < 2; ++j)
            *(u16x8*)&Kout[(size_t)(s0 + row) * 1024 + c0 + cbl + j * 8] = o[j];
    } else {
        constexpr int LDT = 66;
        __shared__ unsigned short t_lds[64 * LDT];
        #pragma unroll
        for (int j = 0; j < 2; ++j)
            *(u16x8*)&t_lds[row * LDT + cbl + j * 8] = o[j];
        __syncthreads();
        const int d = row;
        #pragma unroll
        for (int j = 0; j < 2; ++j) {
            u16x8 w;
            #pragma unroll
            for (int e = 0; e < 8; ++e)
                w[e] = t_lds[(cbl + j * 8 + e) * LDT + d];
            *(u16x8*)&VTout[(size_t)(c0 - 1024 + d) * 2048 + s0 + cbl + j * 8] = w;
        }
    }
}

// ---------------------------------------------------------------------------
// Fallback path kernels (R15-proven): 128x256 gemm8 + combine_kv (2 partials)
// ---------------------------------------------------------------------------
template <typename CT, int CMODE>
__global__ __launch_bounds__(512) void gemm8(
    const unsigned short* __restrict__ A, const unsigned short* __restrict__ B,
    CT* __restrict__ C, int M, int N, int K)
{
    constexpr int ASZ = 128 * 64, BSZ = 256 * 64;
    __shared__ __attribute__((aligned(16))) unsigned short a_lds[3 * ASZ];
    __shared__ __attribute__((aligned(16))) unsigned short b_lds[3 * BSZ];

    const int bm0 = blockIdx.y * 128, bn0 = blockIdx.x * 256;
    const int tid = threadIdx.x, lane = tid & 63, wid = tid >> 6;
    const int wr = wid >> 2, wc = wid & 3;
    const int l15 = lane & 15, koff = (lane >> 4) * 8;
    const int sw = (l15 & 7) << 3;
    const int cb0 = koff ^ sw;
    const int cb1 = (32 + koff) ^ sw;

    f32x4 acc[4][4] = {};

    const size_t kbase = (CMODE == 3) ? (size_t)blockIdx.z * 2048 : 0;

    const unsigned short* ag[2];
    const unsigned short* bg[4];
    #pragma unroll
    for (int p = 0; p < 2; ++p) {
        const int row = (wid + p * 8) * 8 + (lane >> 3);
        ag[p] = A + (size_t)(bm0 + row) * K + (lane & 7) * 8 + kbase;
    }
    #pragma unroll
    for (int p = 0; p < 4; ++p) {
        const int row = (wid + p * 8) * 8 + (lane >> 3);
        bg[p] = B + (size_t)(bn0 + row) * K + (lane & 7) * 8 + kbase;
    }

    const int nt = (CMODE == 3) ? 32 : (K >> 6);

    auto stageA = [&](int s, int kt, int p) {
        gload16(ag[p] + kt, a_lds + s * ASZ + (wid + p * 8) * 512);
    };
    auto stageB = [&](int s, int kt, int p) {
        gload16(bg[p] + kt, b_lds + s * BSZ + (wid + p * 8) * 512);
    };

    #pragma unroll
    for (int p = 0; p < 2; ++p) stageA(0, 0, p);
    #pragma unroll
    for (int p = 0; p < 4; ++p) stageB(0, 0, p);
    #pragma unroll
    for (int p = 0; p < 2; ++p) stageA(1, 64, p);
    #pragma unroll
    for (int p = 0; p < 4; ++p) stageB(1, 64, p);
    WAITVM(6);
    bar();

    int sc = 0;
    for (int t = 0; t < nt; ++t) {
        const unsigned short* ab = a_lds + sc * ASZ;
        const unsigned short* bb = b_lds + sc * BSZ;
        const int ss = (sc >= 1) ? sc - 1 : 2;
        const int kt2 = (t + 2) << 6;
        const bool st = (t + 2) < nt;

        u16x8 af0, af1, af2, af3, bfr[4];

        af0 = *(const u16x8*)&ab[(wr * 64 + 0 * 16 + l15) * 64 + cb0];
        af1 = *(const u16x8*)&ab[(wr * 64 + 1 * 16 + l15) * 64 + cb0];
        af2 = *(const u16x8*)&ab[(wr * 64 + 2 * 16 + l15) * 64 + cb0];
        af3 = *(const u16x8*)&ab[(wr * 64 + 3 * 16 + l15) * 64 + cb0];
        #pragma unroll
        for (int j = 0; j < 4; ++j)
            bfr[j] = *(const u16x8*)&bb[(wc * 64 + j * 16 + l15) * 64 + cb0];
        if (st) { stageA(ss, kt2, 0); stageA(ss, kt2, 1); stageB(ss, kt2, 0); }
        bar();
        __builtin_amdgcn_s_setprio(1);
        #pragma unroll
        for (int j = 0; j < 4; ++j) {
            acc[0][j] = MFMA16(af0, bfr[j], acc[0][j]);
            acc[1][j] = MFMA16(af1, bfr[j], acc[1][j]);
            acc[2][j] = MFMA16(af2, bfr[j], acc[2][j]);
            acc[3][j] = MFMA16(af3, bfr[j], acc[3][j]);
        }
        __builtin_amdgcn_s_setprio(0);

        af0 = *(const u16x8*)&ab[(wr * 64 + 0 * 16 + l15) * 64 + cb1];
        af1 = *(const u16x8*)&ab[(wr * 64 + 1 * 16 + l15) * 64 + cb1];
        af2 = *(const u16x8*)&ab[(wr * 64 + 2 * 16 + l15) * 64 + cb1];
        af3 = *(const u16x8*)&ab[(wr * 64 + 3 * 16 + l15) * 64 + cb1];
        #pragma unroll
        for (int j = 0; j < 4; ++j)
            bfr[j] = *(const u16x8*)&bb[(wc * 64 + j * 16 + l15) * 64 + cb1];
        if (st) {
            stageB(ss, kt2, 1); stageB(ss, kt2, 2); stageB(ss, kt2, 3);
            WAITVM(6);
        } else {
            WAITVM(0);
        }
        bar();
        __builtin_amdgcn_s_setprio(1);
        #pragma unroll
        for (int j = 0; j < 4; ++j) {
            acc[0][j] = MFMA16(af0, bfr[j], acc[0][j]);
            acc[1][j] = MFMA16(af1, bfr[j], acc[1][j]);
            acc[2][j] = MFMA16(af2, bfr[j], acc[2][j]);
            acc[3][j] = MFMA16(af3, bfr[j], acc[3][j]);
        }
        __builtin_amdgcn_s_setprio(0);

        bar();
        sc = (sc == 2) ? 0 : sc + 1;
    }

    CT* Cb = C;
    if constexpr (CMODE == 3)
        Cb = C + (size_t)blockIdx.z * M * N;

    #pragma unroll
    for (int i = 0; i < 4; ++i)
        #pragma unroll
        for (int r = 0; r < 4; ++r) {
            const int row = bm0 + wr * 64 + i * 16 + (lane >> 4) * 4 + r;
            size_t base = (size_t)row * N + bn0 + wc * 64 + l15;
            #pragma unroll
            for (int j = 0; j < 4; ++j)
                storeC(acc[i][j][r], &Cb[base + j * 16]);
        }
}

__global__ __launch_bounds__(256) void combine_kv(
    const float* __restrict__ P, unsigned short* __restrict__ Kout,
    unsigned short* __restrict__ VTout)
{
    const float* P0 = P;
    const float* P1 = P + (size_t)2048 * 2048;
    const int s0 = blockIdx.y * 64, c0 = blockIdx.x * 64;
    const int tid = threadIdx.x;
    const int row = tid >> 2;
    const int cbl = (tid & 3) * 16;
    const size_t gbase = (size_t)(s0 + row) * 2048 + c0 + cbl;
    u16x8 o[2];
    #pragma unroll
    for (int j = 0; j < 2; ++j) {
        float4 a0 = *(const float4*)&P0[gbase + j * 8];
        float4 b0 = *(const float4*)&P1[gbase + j * 8];
        float4 a1 = *(const float4*)&P0[gbase + j * 8 + 4];
        float4 b1 = *(const float4*)&P1[gbase + j * 8 + 4];
        o[j][0] = f2bf(a0.x + b0.x); o[j][1] = f2bf(a0.y + b0.y);
        o[j][2] = f2bf(a0.z + b0.z); o[j][3] = f2bf(a0.w + b0.w);
        o[j][4] = f2bf(a1.x + b1.x); o[j][5] = f2bf(a1.y + b1.y);
        o[j][6] = f2bf(a1.z + b1.z); o[j][7] = f2bf(a1.w + b1.w);
    }
    if (c0 < 1024) {
        #pragma unroll
        for (int j = 0; j < 2; ++j)
            *(u16x8*)&Kout[(size_t)(s0 + row) * 1024 + c0 + cbl + j * 8] = o[j];
    } else {
        constexpr int LDT = 66;
        __shared__ unsigned short t_lds[64 * LDT];
        #pragma unroll
        for (int j = 0; j < 2; ++j)
            *(u16x8*)&t_lds[row * LDT + cbl + j * 8] = o[j];
        __syncthreads();
        const int d = row;
        #pragma unroll
        for (int j = 0; j < 2; ++j) {
            u16x8 w;
            #pragma unroll
            for (int e = 0; e < 8; ++e)
                w[e] = t_lds[(cbl + j * 8 + e) * LDT + d];
            *(u16x8*)&VTout[(size_t)(c0 - 1024 + d) * 2048 + s0 + cbl + j * 8] = w;
        }
    }
}

// ---------------------------------------------------------------------------
// Merged RoPE + RMSNorm (Q and K in one dispatch), in-place on bf16.
// ---------------------------------------------------------------------------
__device__ void rope_row(unsigned short* __restrict__ X,
                         const float* __restrict__ W,
                         float fpos, int rowstride, size_t s, int h, int t8,
                         float outscale)
{
    unsigned short* p = X + s * rowstride + h * 128 + t8 * 8;
    u16x8 lo = *(u16x8*)p;
    u16x8 hi = *(u16x8*)(p + 64);
    float na[8], nb[8];
    float ss = 0.f;
    #pragma unroll
    for (int j = 0; j < 8; ++j) {
        const int d = t8 * 8 + j;
        float inv = expf(-0.14391156831212787f * (float)d);
        float fr = fpos * inv;
        float c = cosf(fr), sn = sinf(fr);
        float a = bf2f(lo[j]), b = bf2f(hi[j]);
        na[j] = a * c - b * sn;
        nb[j] = b * c + a * sn;
        ss += na[j] * na[j] + nb[j] * nb[j];
    }
    ss += __shfl_xor(ss, 1, 8);
    ss += __shfl_xor(ss, 2, 8);
    ss += __shfl_xor(ss, 4, 8);
    const float rn = rsqrtf(ss * (1.0f / 128.0f) + 1e-6f) * outscale;
    #pragma unroll
    for (int j = 0; j < 8; ++j) {
        const int d = t8 * 8 + j;
        lo[j] = f2bf(na[j] * rn * W[d]);
        hi[j] = f2bf(nb[j] * rn * W[d + 64]);
    }
    *(u16x8*)p = lo;
    *(u16x8*)(p + 64) = hi;
}

__global__ void rope_all(unsigned short* __restrict__ Q,
                         unsigned short* __restrict__ K,
                         const int* __restrict__ pos_ids,
                         const float* __restrict__ qw,
                         const float* __restrict__ kw,
                         float qscale)
{
    const int bid = blockIdx.x;
    const int tid = threadIdx.x;
    if (bid < 2048) {
        rope_row(Q, qw, (float)pos_ids[bid], 4096, (size_t)bid,
                 tid >> 3, tid & 7, qscale);
    } else {
        const size_t s = (size_t)(bid - 2048) * 4 + (tid >> 6);
        rope_row(K, kw, (float)pos_ids[s], 1024, s,
                 (tid & 63) >> 3, tid & 7, 1.0f);
    }
}

// ---------------------------------------------------------------------------
// Causal flash attention (R11-proven), V^T input, bf16 swizzled output.
// ---------------------------------------------------------------------------
__global__ __launch_bounds__(256, 2) void attn_kernel(
    const unsigned short* __restrict__ Q, const unsigned short* __restrict__ K,
    const unsigned short* __restrict__ VT, unsigned short* __restrict__ O)
{
    constexpr int LDK = 136, LDV = 72, LDP = 72;
    __shared__ __attribute__((aligned(16))) unsigned short k_lds[64 * LDK];
    __shared__ __attribute__((aligned(16))) unsigned short v_lds[128 * LDV];
    __shared__ __attribute__((aligned(16))) unsigned short p_lds[4 * 32 * LDP];

    const int bid = blockIdx.x;
    const int kvh = bid & 7;
    const int rest = bid >> 3;
    const int h = kvh * 4 + (rest & 3);
    const int qb = 15 - (rest >> 2);
    const int q0 = qb * 128;
    const int tid = threadIdx.x, lane = tid & 63, wid = tid >> 6;
    const int l15 = lane & 15, g4 = (lane >> 4) * 4, koff = (lane >> 4) * 8;
    const int qw = q0 + wid * 32;

    u16x8 qf[2][4];
    #pragma unroll
    for (int qt = 0; qt < 2; ++qt)
        #pragma unroll
        for (int kk = 0; kk < 4; ++kk)
            qf[qt][kk] = *(const u16x8*)&Q[(size_t)(qw + qt * 16 + l15) * 4096 +
                                           h * 128 + kk * 32 + koff];

    f32x4 o_acc[2][8] = {};
    float m_r[2] = {-1e30f, -1e30f}, l_r[2] = {0.f, 0.f};

    const int kr = tid >> 2, kd = (tid & 3) * 32;
    const int vr = tid >> 1, vc = (tid & 1) * 32;
    const unsigned short* kg = K + (size_t)kvh * 128 + kd;
    const unsigned short* vg = VT + (size_t)(kvh * 128 + vr) * 2048 + vc;

    const int nchunk = qb * 2 + 2;
    u16x8 kst[4], vst[4];
    #pragma unroll
    for (int j = 0; j < 4; ++j) {
        kst[j] = *(const u16x8*)&kg[(size_t)kr * 1024 + j * 8];
        vst[j] = *(const u16x8*)&vg[j * 8];
    }

    for (int ch = 0; ch < nchunk; ++ch) {
        const int kv0 = ch * 64;
        __syncthreads();
        #pragma unroll
        for (int j = 0; j < 4; ++j) {
            *(u16x8*)&k_lds[kr * LDK + kd + j * 8] = kst[j];
            *(u16x8*)&v_lds[vr * LDV + vc + j * 8] = vst[j];
        }
        __syncthreads();
        if (ch + 1 < nchunk) {
            const int kv1 = kv0 + 64;
            #pragma unroll
            for (int j = 0; j < 4; ++j) {
                kst[j] = *(const u16x8*)&kg[(size_t)(kv1 + kr) * 1024 + j * 8];
                vst[j] = *(const u16x8*)&vg[kv1 + j * 8];
            }
        }

        if (kv0 <= qw + 31) {
            f32x4 sacc[2][4] = {};
            #pragma unroll
            for (int kk = 0; kk < 4; ++kk)
                #pragma unroll
                for (int jt = 0; jt < 4; ++jt) {
                    u16x8 kf = *(u16x8*)&k_lds[(jt * 16 + l15) * LDK + kk * 32 + koff];
                    #pragma unroll
                    for (int qt = 0; qt < 2; ++qt)
                        sacc[qt][jt] = MFMA16(kf, qf[qt][kk], sacc[qt][jt]);
                }

            const bool needmask = (kv0 + 63 > qw);
            #pragma unroll
            for (int qt = 0; qt < 2; ++qt) {
                const int q = qw + qt * 16 + l15;
                if (needmask) {
                    #pragma unroll
                    for (int jt = 0; jt < 4; ++jt)
                        #pragma unroll
                        for (int r = 0; r < 4; ++r)
                            if (kv0 + jt * 16 + g4 + r > q) sacc[qt][jt][r] = -1e9f;
                }
                float pmax = sacc[qt][0][0];
                #pragma unroll
                for (int jt = 0; jt < 4; ++jt)
                    #pragma unroll
                    for (int r = 0; r < 4; ++r)
                        pmax = fmaxf(pmax, sacc[qt][jt][r]);
                pmax = fmaxf(pmax, __shfl_xor(pmax, 16));
                pmax = fmaxf(pmax, __shfl_xor(pmax, 32));
                if (__any(pmax > m_r[qt] + 11.5415603f)) {
                    float mnew = fmaxf(m_r[qt], pmax);
                    float alpha = fexp2(m_r[qt] - mnew);
                    m_r[qt] = mnew;
                    l_r[qt] *= alpha;
                    float arow[4];
                    #pragma unroll
                    for (int r = 0; r < 4; ++r)
                        arow[r] = __shfl(alpha, g4 + r, 16);
                    #pragma unroll
                    for (int nt = 0; nt < 8; ++nt)
                        #pragma unroll
                        for (int r = 0; r < 4; ++r)
                            o_acc[qt][nt][r] *= arow[r];
                }
                float ps = 0.f;
                #pragma unroll
                for (int jt = 0; jt < 4; ++jt)
                    #pragma unroll
                    for (int r = 0; r < 4; ++r) {
                        float e = fexp2(sacc[qt][jt][r] - m_r[qt]);
                        sacc[qt][jt][r] = e;
                        ps += e;
                    }
                ps += __shfl_xor(ps, 16);
                ps += __shfl_xor(ps, 32);
                l_r[qt] += ps;
                const int prow = (wid * 32 + qt * 16 + l15) * LDP;
                #pragma unroll
                for (int jt = 0; jt < 4; ++jt) {
                    u16x4 w;
                    #pragma unroll
                    for (int r = 0; r < 4; ++r) w[r] = f2bf(sacc[qt][jt][r]);
                    *(u16x4*)&p_lds[prow + jt * 16 + g4] = w;
                }
            }

            u16x8 pf[2][2];
            #pragma unroll
            for (int qt = 0; qt < 2; ++qt)
                #pragma unroll
                for (int ks = 0; ks < 2; ++ks)
                    pf[qt][ks] = *(u16x8*)&p_lds[(wid * 32 + qt * 16 + l15) * LDP +
                                                 ks * 32 + koff];
            #pragma unroll
            for (int nt = 0; nt < 8; ++nt)
                #pragma unroll
                for (int ks = 0; ks < 2; ++ks) {
                    u16x8 vf = *(u16x8*)&v_lds[(nt * 16 + l15) * LDV + ks * 32 + koff];
                    #pragma unroll
                    for (int qt = 0; qt < 2; ++qt)
                        o_acc[qt][nt] = MFMA16(pf[qt][ks], vf, o_acc[qt][nt]);
                }
        }
    }

    #pragma unroll
    for (int qt = 0; qt < 2; ++qt) {
        float lrow[4];
        #pragma unroll
        for (int r = 0; r < 4; ++r)
            lrow[r] = __shfl(l_r[qt], g4 + r, 16);
        #pragma unroll
        for (int r = 0; r < 4; ++r) {
            float inv_l = 1.0f / lrow[r];
            int row = qw + qt * 16 + g4 + r;
            const int r7s = (row & 7) << 3;
            #pragma unroll
            for (int nt = 0; nt < 8; ++nt) {
                int col = h * 128 + nt * 16 + l15;
                O[(size_t)row * 4096 + (col ^ r7s)] =
                    f2bf(o_acc[qt][nt][r] * inv_l);
            }
        }
    }
}

// ---------------------------------------------------------------------------
extern "C" void kernel_launch(void* const* d_in, const int* in_sizes, int n_in,
                              void* d_out, int out_size, void* d_ws, size_t ws_size,
                              hipStream_t stream)
{
    (void)in_sizes; (void)n_in; (void)out_size;
    const float* hidden = (const float*)d_in[0];
    const float* wq     = (const float*)d_in[1];
    const float* wk     = (const float*)d_in[2];
    const float* wv     = (const float*)d_in[3];
    const float* wo     = (const float*)d_in[4];
    const float* qnw    = (const float*)d_in[5];
    const float* knw    = (const float*)d_in[6];
    const int*   pos    = (const int*)d_in[8];
    float* out = (float*)d_out;

    const size_t MB = 1024 * 1024;
    char* ws = (char*)d_ws;
    unsigned short* q_ws  = (unsigned short*)(ws);             // 16 MB
    unsigned short* k_ws  = (unsigned short*)(ws + 16 * MB);   //  4 MB
    unsigned short* vt_ws = (unsigned short*)(ws + 20 * MB);   //  4 MB
    unsigned short* hb    = (unsigned short*)(ws + 24 * MB);   // 16 MB (-> a_ws)
    unsigned short* a_ws  = hb;
    unsigned short* wqt   = (unsigned short*)(ws + 40 * MB);   // 32 MB
    float*          kvP   = (float*)(ws + 40 * MB);            // 32 MB (fallback)
    unsigned short* wkt   = (unsigned short*)(ws + 72 * MB);   //  8 MB (+wvt adjacent)
    unsigned short* wot   = (unsigned short*)(ws + 88 * MB);   // 32 MB
    float*          Ppart = (float*)(ws + 120 * MB);           // 64 MB (big path)

    prep_all<<<6656, 256, 0, stream>>>(hidden, wq, wk, wv, wo,
                                       hb, wqt, wkt, wot);

    if (ws_size >= (size_t)184 * MB) {
        // 256^2 K-split path
        gemm256<<<dim3(16, 8, 2), 512, 0, stream>>>(
            hb, wqt, Ppart, 2048, 4096, 2048);
        combine2_bf16<<<4096, 256, 0, stream>>>(
            Ppart, q_ws, (size_t)2048 * 4096);
        gemm256<<<dim3(8, 8, 4), 512, 0, stream>>>(
            hb, wkt, Ppart, 2048, 2048, 1024);
        combine_kv4<<<dim3(32, 32), 256, 0, stream>>>(Ppart, k_ws, vt_ws);

        rope_all<<<2560, 256, 0, stream>>>(q_ws, k_ws, pos, qnw, knw,
                                           0.12751743341633942f);
        attn_kernel<<<512, 256, 0, stream>>>(q_ws, k_ws, vt_ws, a_ws);

        gemm256<<<dim3(16, 8, 2), 512, 0, stream>>>(
            a_ws, wot, Ppart, 2048, 4096, 2048);
        combine2_f32<<<8192, 256, 0, stream>>>(
            Ppart, out, (size_t)2048 * 4096);
    } else {
        // fallback: R15-proven path
        gemm8<unsigned short, 0><<<dim3(16, 16), 512, 0, stream>>>(
            hb, wqt, q_ws, 2048, 4096, 4096);
        gemm8<float, 3><<<dim3(8, 16, 2), 512, 0, stream>>>(
            hb, wkt, kvP, 2048, 2048, 4096);
        combine_kv<<<dim3(32, 32), 256, 0, stream>>>(kvP, k_ws, vt_ws);

        rope_all<<<2560, 256, 0, stream>>>(q_ws, k_ws, pos, qnw, knw,
                                           0.12751743341633942f);
        attn_kernel<<<512, 256, 0, stream>>>(q_ws, k_ws, vt_ws, a_ws);

        gemm8<float, 0><<<dim3(16, 16), 512, 0, stream>>>(
            a_ws, wot, out, 2048, 4096, 4096);
    }
}

// Round 17
// 327.496 us; speedup vs baseline: 1.1320x; 1.1320x over previous
//
#include <hip/hip_runtime.h>

typedef __bf16 bf16x8 __attribute__((ext_vector_type(8)));
typedef float f32x4 __attribute__((ext_vector_type(4)));
typedef unsigned short u16x8 __attribute__((ext_vector_type(8)));
typedef unsigned short u16x4 __attribute__((ext_vector_type(4)));
typedef unsigned short u16x2 __attribute__((ext_vector_type(2)));

__device__ inline unsigned short f2bf(float f) {
    return __builtin_bit_cast(unsigned short, (__bf16)f);
}
__device__ inline float bf2f(unsigned short u) {
    return (float)__builtin_bit_cast(__bf16, u);
}

// native 2^x (v_exp_f32 is exp2 on gfx950); avoids libm header clash
__device__ __forceinline__ float fexp2(float x) {
    float r;
    asm("v_exp_f32 %0, %1" : "=v"(r) : "v"(x));
    return r;
}

__device__ inline void storeC(float v, float* p) { *p = v; }
__device__ inline void storeC(float v, unsigned short* p) { *p = f2bf(v); }

#define MFMA16(a, b, c) __builtin_amdgcn_mfma_f32_16x16x32_bf16( \
    __builtin_bit_cast(bf16x8, a), __builtin_bit_cast(bf16x8, b), (c), 0, 0, 0)

// async global->LDS, 16B per lane; LDS dest = wave-uniform base + lane*16
__device__ inline void gload16(const unsigned short* g, unsigned short* l) {
    __builtin_amdgcn_global_load_lds(
        (const __attribute__((address_space(1))) unsigned int*)(g),
        (__attribute__((address_space(3))) unsigned int*)(l), 16, 0, 0);
}

__device__ __forceinline__ void bar() {
    asm volatile("" ::: "memory");
    __builtin_amdgcn_s_barrier();
    asm volatile("" ::: "memory");
}
#define WAITVM(N) asm volatile("s_waitcnt vmcnt(" #N ")" ::: "memory")

// ---------------------------------------------------------------------------
// Merged prep (R15-proven): convert + 4 weight transposes, one dispatch.
// 128x128 transpose tiles, LDS stride 130 (conflict-free), output swizzled
// per GEMM contract: within each 64-hw k-block, 8-slot ^= (n&7).
// ---------------------------------------------------------------------------
__device__ void transpose_tile128(const float* __restrict__ W,
                                  unsigned short* __restrict__ WT,
                                  int K, int N, int bx, int by,
                                  unsigned short* t_lds)
{
    constexpr int LDT = 130;
    const int kt = bx * 128, nt = by * 128;
    const int tid = threadIdx.x;
    const int c = (tid & 31) * 4;
    const int r0 = tid >> 5;
    #pragma unroll
    for (int p = 0; p < 16; ++p) {
        const int r = p * 8 + r0;
        float4 v = *(const float4*)&W[(size_t)(kt + r) * N + nt + c];
        u16x4 h;
        h[0] = f2bf(v.x); h[1] = f2bf(v.y); h[2] = f2bf(v.z); h[3] = f2bf(v.w);
        *(u16x4*)&t_lds[r * LDT + c] = h;
    }
    __syncthreads();
    const int kc = (tid >> 4) * 8;
    const int n0 = tid & 15;
    #pragma unroll
    for (int p = 0; p < 8; ++p) {
        const int n = p * 16 + n0;
        u16x8 o;
        #pragma unroll
        for (int j = 0; j < 8; ++j)
            o[j] = t_lds[(kc + j) * LDT + n];
        const int swz = (kc & 64) | ((kc & 63) ^ ((n & 7) << 3));
        *(u16x8*)&WT[(size_t)(nt + n) * K + kt + swz] = o;
    }
}

__global__ __launch_bounds__(256) void prep_all(
    const float* __restrict__ hidden, const float* __restrict__ wq,
    const float* __restrict__ wk, const float* __restrict__ wv,
    const float* __restrict__ wo, unsigned short* __restrict__ hb,
    unsigned short* __restrict__ wqt, unsigned short* __restrict__ wkt,
    unsigned short* __restrict__ wot)
{
    __shared__ __attribute__((aligned(16))) unsigned short t_lds[128 * 130];
    const int bid = blockIdx.x;
    if (bid < 4096) {
        const size_t i = ((size_t)bid * 256 + threadIdx.x) * 8;
        const size_t row7 = (i >> 12) & 7;
        float4 v0 = *(const float4*)&hidden[i];
        float4 v1 = *(const float4*)&hidden[i + 4];
        u16x8 o;
        o[0] = f2bf(v0.x); o[1] = f2bf(v0.y); o[2] = f2bf(v0.z); o[3] = f2bf(v0.w);
        o[4] = f2bf(v1.x); o[5] = f2bf(v1.y); o[6] = f2bf(v1.z); o[7] = f2bf(v1.w);
        *(u16x8*)&hb[i ^ (row7 << 3)] = o;
    } else if (bid < 5120) {
        const int tb = bid - 4096;
        transpose_tile128(wq, wqt, 4096, 4096, tb & 31, tb >> 5, t_lds);
    } else if (bid < 5376) {
        const int tb = bid - 5120;
        transpose_tile128(wk, wkt, 4096, 1024, tb & 31, tb >> 5, t_lds);
    } else if (bid < 5632) {
        const int tb = bid - 5376;
        transpose_tile128(wv, wkt + (size_t)1024 * 4096, 4096, 1024,
                          tb & 31, tb >> 5, t_lds);
    } else {
        const int tb = bid - 5632;
        transpose_tile128(wo, wot, 4096, 4096, tb & 31, tb >> 5, t_lds);
    }
}

// ---------------------------------------------------------------------------
// Phase-interleaved GEMM (R11-exact, best measured): C[M,N] = A[M,K] * B^T,
// A/B bf16 K-major, sources pre-swizzled. 128x256 tile, BK=64, 8 waves
// (2Mx4N of 64x64), TRIPLE-buffered LDS, 2 phases + 3 barriers per K-tile,
// counted vmcnt(6) once per tile.
// CMODE 0: full K, C[M][N].
// CMODE 3: K-split over blockIdx.z (each z does 2048 of K), raw f32 tile
//          stored to C + z*M*N (partials; combined by combine_kv).
// ---------------------------------------------------------------------------
template <typename CT, int CMODE>
__global__ __launch_bounds__(512) void gemm8(
    const unsigned short* __restrict__ A, const unsigned short* __restrict__ B,
    CT* __restrict__ C, int M, int N, int K)
{
    constexpr int ASZ = 128 * 64, BSZ = 256 * 64;
    __shared__ __attribute__((aligned(16))) unsigned short a_lds[3 * ASZ];
    __shared__ __attribute__((aligned(16))) unsigned short b_lds[3 * BSZ];

    const int bm0 = blockIdx.y * 128, bn0 = blockIdx.x * 256;
    const int tid = threadIdx.x, lane = tid & 63, wid = tid >> 6;
    const int wr = wid >> 2, wc = wid & 3;
    const int l15 = lane & 15, koff = (lane >> 4) * 8;
    const int sw = (l15 & 7) << 3;
    const int cb0 = koff ^ sw;
    const int cb1 = (32 + koff) ^ sw;

    f32x4 acc[4][4] = {};

    const size_t kbase = (CMODE == 3) ? (size_t)blockIdx.z * 2048 : 0;

    const unsigned short* ag[2];
    const unsigned short* bg[4];
    #pragma unroll
    for (int p = 0; p < 2; ++p) {
        const int row = (wid + p * 8) * 8 + (lane >> 3);
        ag[p] = A + (size_t)(bm0 + row) * K + (lane & 7) * 8 + kbase;
    }
    #pragma unroll
    for (int p = 0; p < 4; ++p) {
        const int row = (wid + p * 8) * 8 + (lane >> 3);
        bg[p] = B + (size_t)(bn0 + row) * K + (lane & 7) * 8 + kbase;
    }

    const int nt = (CMODE == 3) ? 32 : (K >> 6);

    auto stageA = [&](int s, int kt, int p) {
        gload16(ag[p] + kt, a_lds + s * ASZ + (wid + p * 8) * 512);
    };
    auto stageB = [&](int s, int kt, int p) {
        gload16(bg[p] + kt, b_lds + s * BSZ + (wid + p * 8) * 512);
    };

    #pragma unroll
    for (int p = 0; p < 2; ++p) stageA(0, 0, p);
    #pragma unroll
    for (int p = 0; p < 4; ++p) stageB(0, 0, p);
    #pragma unroll
    for (int p = 0; p < 2; ++p) stageA(1, 64, p);
    #pragma unroll
    for (int p = 0; p < 4; ++p) stageB(1, 64, p);
    WAITVM(6);
    bar();

    int sc = 0;
    for (int t = 0; t < nt; ++t) {
        const unsigned short* ab = a_lds + sc * ASZ;
        const unsigned short* bb = b_lds + sc * BSZ;
        const int ss = (sc >= 1) ? sc - 1 : 2;
        const int kt2 = (t + 2) << 6;
        const bool st = (t + 2) < nt;

        u16x8 af0, af1, af2, af3, bfr[4];

        // ---- Phase A: kk0 reads + 3 gloads, then 16 MFMA
        af0 = *(const u16x8*)&ab[(wr * 64 + 0 * 16 + l15) * 64 + cb0];
        af1 = *(const u16x8*)&ab[(wr * 64 + 1 * 16 + l15) * 64 + cb0];
        af2 = *(const u16x8*)&ab[(wr * 64 + 2 * 16 + l15) * 64 + cb0];
        af3 = *(const u16x8*)&ab[(wr * 64 + 3 * 16 + l15) * 64 + cb0];
        #pragma unroll
        for (int j = 0; j < 4; ++j)
            bfr[j] = *(const u16x8*)&bb[(wc * 64 + j * 16 + l15) * 64 + cb0];
        if (st) { stageA(ss, kt2, 0); stageA(ss, kt2, 1); stageB(ss, kt2, 0); }
        bar();
        __builtin_amdgcn_s_setprio(1);
        #pragma unroll
        for (int j = 0; j < 4; ++j) {
            acc[0][j] = MFMA16(af0, bfr[j], acc[0][j]);
            acc[1][j] = MFMA16(af1, bfr[j], acc[1][j]);
            acc[2][j] = MFMA16(af2, bfr[j], acc[2][j]);
            acc[3][j] = MFMA16(af3, bfr[j], acc[3][j]);
        }
        __builtin_amdgcn_s_setprio(0);

        // ---- Phase B: kk1 reads + 3 gloads + counted vmcnt, then 16 MFMA
        af0 = *(const u16x8*)&ab[(wr * 64 + 0 * 16 + l15) * 64 + cb1];
        af1 = *(const u16x8*)&ab[(wr * 64 + 1 * 16 + l15) * 64 + cb1];
        af2 = *(const u16x8*)&ab[(wr * 64 + 2 * 16 + l15) * 64 + cb1];
        af3 = *(const u16x8*)&ab[(wr * 64 + 3 * 16 + l15) * 64 + cb1];
        #pragma unroll
        for (int j = 0; j < 4; ++j)
            bfr[j] = *(const u16x8*)&bb[(wc * 64 + j * 16 + l15) * 64 + cb1];
        if (st) {
            stageB(ss, kt2, 1); stageB(ss, kt2, 2); stageB(ss, kt2, 3);
            WAITVM(6);
        } else {
            WAITVM(0);
        }
        bar();
        __builtin_amdgcn_s_setprio(1);
        #pragma unroll
        for (int j = 0; j < 4; ++j) {
            acc[0][j] = MFMA16(af0, bfr[j], acc[0][j]);
            acc[1][j] = MFMA16(af1, bfr[j], acc[1][j]);
            acc[2][j] = MFMA16(af2, bfr[j], acc[2][j]);
            acc[3][j] = MFMA16(af3, bfr[j], acc[3][j]);
        }
        __builtin_amdgcn_s_setprio(0);

        bar();              // tile end: all reads of slot sc complete
        sc = (sc == 2) ? 0 : sc + 1;
    }

    CT* Cb = C;
    if constexpr (CMODE == 3)
        Cb = C + (size_t)blockIdx.z * M * N;

    #pragma unroll
    for (int i = 0; i < 4; ++i)
        #pragma unroll
        for (int r = 0; r < 4; ++r) {
            const int row = bm0 + wr * 64 + i * 16 + (lane >> 4) * 4 + r;
            size_t base = (size_t)row * N + bn0 + wc * 64 + l15;
            #pragma unroll
            for (int j = 0; j < 4; ++j)
                storeC(acc[i][j][r], &Cb[base + j * 16]);
        }
}

// ---------------------------------------------------------------------------
// combine_kv: P0+P1 (f32 [2][2048][2048] K-split partials) ->
//   cols <1024  : k_ws bf16 [2048][1024] (direct)
//   cols >=1024 : vt_ws bf16 [1024][2048] (transposed via LDS)
// ---------------------------------------------------------------------------
__global__ __launch_bounds__(256) void combine_kv(
    const float* __restrict__ P, unsigned short* __restrict__ Kout,
    unsigned short* __restrict__ VTout)
{
    const float* P0 = P;
    const float* P1 = P + (size_t)2048 * 2048;
    const int s0 = blockIdx.y * 64, c0 = blockIdx.x * 64;
    const int tid = threadIdx.x;
    const int row = tid >> 2;
    const int cbl = (tid & 3) * 16;
    const size_t gbase = (size_t)(s0 + row) * 2048 + c0 + cbl;
    u16x8 o[2];
    #pragma unroll
    for (int j = 0; j < 2; ++j) {
        float4 a0 = *(const float4*)&P0[gbase + j * 8];
        float4 b0 = *(const float4*)&P1[gbase + j * 8];
        float4 a1 = *(const float4*)&P0[gbase + j * 8 + 4];
        float4 b1 = *(const float4*)&P1[gbase + j * 8 + 4];
        o[j][0] = f2bf(a0.x + b0.x); o[j][1] = f2bf(a0.y + b0.y);
        o[j][2] = f2bf(a0.z + b0.z); o[j][3] = f2bf(a0.w + b0.w);
        o[j][4] = f2bf(a1.x + b1.x); o[j][5] = f2bf(a1.y + b1.y);
        o[j][6] = f2bf(a1.z + b1.z); o[j][7] = f2bf(a1.w + b1.w);
    }
    if (c0 < 1024) {
        #pragma unroll
        for (int j = 0; j < 2; ++j)
            *(u16x8*)&Kout[(size_t)(s0 + row) * 1024 + c0 + cbl + j * 8] = o[j];
    } else {
        constexpr int LDT = 66;
        __shared__ unsigned short t_lds[64 * LDT];
        #pragma unroll
        for (int j = 0; j < 2; ++j)
            *(u16x8*)&t_lds[row * LDT + cbl + j * 8] = o[j];
        __syncthreads();
        const int d = row;
        #pragma unroll
        for (int j = 0; j < 2; ++j) {
            u16x8 w;
            #pragma unroll
            for (int e = 0; e < 8; ++e)
                w[e] = t_lds[(cbl + j * 8 + e) * LDT + d];
            *(u16x8*)&VTout[(size_t)(c0 - 1024 + d) * 2048 + s0 + cbl + j * 8] = w;
        }
    }
}

// ---------------------------------------------------------------------------
// Merged RoPE + RMSNorm (Q and K in one dispatch), in-place on bf16.
//   bid [0,2048)    : Q row s=bid, H=32 (256 threads, 8 per head)
//   bid [2048,2560) : K rows s=(bid-2048)*4 + (tid>>6), H=8 (64 thr/row)
// ---------------------------------------------------------------------------
__device__ void rope_row(unsigned short* __restrict__ X,
                         const float* __restrict__ W,
                         float fpos, int rowstride, size_t s, int h, int t8,
                         float outscale)
{
    unsigned short* p = X + s * rowstride + h * 128 + t8 * 8;
    u16x8 lo = *(u16x8*)p;
    u16x8 hi = *(u16x8*)(p + 64);
    float na[8], nb[8];
    float ss = 0.f;
    #pragma unroll
    for (int j = 0; j < 8; ++j) {
        const int d = t8 * 8 + j;
        float inv = expf(-0.14391156831212787f * (float)d);
        float fr = fpos * inv;
        float c = cosf(fr), sn = sinf(fr);
        float a = bf2f(lo[j]), b = bf2f(hi[j]);
        na[j] = a * c - b * sn;
        nb[j] = b * c + a * sn;
        ss += na[j] * na[j] + nb[j] * nb[j];
    }
    ss += __shfl_xor(ss, 1, 8);
    ss += __shfl_xor(ss, 2, 8);
    ss += __shfl_xor(ss, 4, 8);
    const float rn = rsqrtf(ss * (1.0f / 128.0f) + 1e-6f) * outscale;
    #pragma unroll
    for (int j = 0; j < 8; ++j) {
        const int d = t8 * 8 + j;
        lo[j] = f2bf(na[j] * rn * W[d]);
        hi[j] = f2bf(nb[j] * rn * W[d + 64]);
    }
    *(u16x8*)p = lo;
    *(u16x8*)(p + 64) = hi;
}

__global__ void rope_all(unsigned short* __restrict__ Q,
                         unsigned short* __restrict__ K,
                         const int* __restrict__ pos_ids,
                         const float* __restrict__ qw,
                         const float* __restrict__ kw,
                         float qscale)
{
    const int bid = blockIdx.x;
    const int tid = threadIdx.x;
    if (bid < 2048) {
        rope_row(Q, qw, (float)pos_ids[bid], 4096, (size_t)bid,
                 tid >> 3, tid & 7, qscale);
    } else {
        const size_t s = (size_t)(bid - 2048) * 4 + (tid >> 6);
        rope_row(K, kw, (float)pos_ids[s], 1024, s,
                 (tid & 63) >> 3, tid & 7, 1.0f);
    }
}

// ---------------------------------------------------------------------------
// Causal flash attention (R11-proven), V^T input, bf16 swizzled output.
// Swapped QK^T (mfma(K,Q) -> S^T): softmax is lane-local (q = lane&15),
// row-reduce = 2 shfls. Defer-rescale. Packed b64 P-writes. exp2-domain
// softmax (log2e folded into Q scale); fexp2 = native v_exp_f32.
// Grid: bid&7 = kv-head (XCD L2 affinity), heavy q-blocks first.
// ---------------------------------------------------------------------------
__global__ __launch_bounds__(256, 2) void attn_kernel(
    const unsigned short* __restrict__ Q, const unsigned short* __restrict__ K,
    const unsigned short* __restrict__ VT, unsigned short* __restrict__ O)
{
    constexpr int LDK = 136, LDV = 72, LDP = 72;
    __shared__ __attribute__((aligned(16))) unsigned short k_lds[64 * LDK];
    __shared__ __attribute__((aligned(16))) unsigned short v_lds[128 * LDV];
    __shared__ __attribute__((aligned(16))) unsigned short p_lds[4 * 32 * LDP];

    const int bid = blockIdx.x;
    const int kvh = bid & 7;
    const int rest = bid >> 3;
    const int h = kvh * 4 + (rest & 3);
    const int qb = 15 - (rest >> 2);
    const int q0 = qb * 128;
    const int tid = threadIdx.x, lane = tid & 63, wid = tid >> 6;
    const int l15 = lane & 15, g4 = (lane >> 4) * 4, koff = (lane >> 4) * 8;
    const int qw = q0 + wid * 32;

    u16x8 qf[2][4];
    #pragma unroll
    for (int qt = 0; qt < 2; ++qt)
        #pragma unroll
        for (int kk = 0; kk < 4; ++kk)
            qf[qt][kk] = *(const u16x8*)&Q[(size_t)(qw + qt * 16 + l15) * 4096 +
                                           h * 128 + kk * 32 + koff];

    f32x4 o_acc[2][8] = {};
    float m_r[2] = {-1e30f, -1e30f}, l_r[2] = {0.f, 0.f};

    const int kr = tid >> 2, kd = (tid & 3) * 32;
    const int vr = tid >> 1, vc = (tid & 1) * 32;
    const unsigned short* kg = K + (size_t)kvh * 128 + kd;
    const unsigned short* vg = VT + (size_t)(kvh * 128 + vr) * 2048 + vc;

    const int nchunk = qb * 2 + 2;
    u16x8 kst[4], vst[4];
    #pragma unroll
    for (int j = 0; j < 4; ++j) {
        kst[j] = *(const u16x8*)&kg[(size_t)kr * 1024 + j * 8];
        vst[j] = *(const u16x8*)&vg[j * 8];
    }

    for (int ch = 0; ch < nchunk; ++ch) {
        const int kv0 = ch * 64;
        __syncthreads();
        #pragma unroll
        for (int j = 0; j < 4; ++j) {
            *(u16x8*)&k_lds[kr * LDK + kd + j * 8] = kst[j];
            *(u16x8*)&v_lds[vr * LDV + vc + j * 8] = vst[j];
        }
        __syncthreads();
        if (ch + 1 < nchunk) {
            const int kv1 = kv0 + 64;
            #pragma unroll
            for (int j = 0; j < 4; ++j) {
                kst[j] = *(const u16x8*)&kg[(size_t)(kv1 + kr) * 1024 + j * 8];
                vst[j] = *(const u16x8*)&vg[kv1 + j * 8];
            }
        }

        if (kv0 <= qw + 31) {
            f32x4 sacc[2][4] = {};
            #pragma unroll
            for (int kk = 0; kk < 4; ++kk)
                #pragma unroll
                for (int jt = 0; jt < 4; ++jt) {
                    u16x8 kf = *(u16x8*)&k_lds[(jt * 16 + l15) * LDK + kk * 32 + koff];
                    #pragma unroll
                    for (int qt = 0; qt < 2; ++qt)
                        sacc[qt][jt] = MFMA16(kf, qf[qt][kk], sacc[qt][jt]);
                }

            const bool needmask = (kv0 + 63 > qw);
            #pragma unroll
            for (int qt = 0; qt < 2; ++qt) {
                const int q = qw + qt * 16 + l15;
                if (needmask) {
                    #pragma unroll
                    for (int jt = 0; jt < 4; ++jt)
                        #pragma unroll
                        for (int r = 0; r < 4; ++r)
                            if (kv0 + jt * 16 + g4 + r > q) sacc[qt][jt][r] = -1e9f;
                }
                float pmax = sacc[qt][0][0];
                #pragma unroll
                for (int jt = 0; jt < 4; ++jt)
                    #pragma unroll
                    for (int r = 0; r < 4; ++r)
                        pmax = fmaxf(pmax, sacc[qt][jt][r]);
                pmax = fmaxf(pmax, __shfl_xor(pmax, 16));
                pmax = fmaxf(pmax, __shfl_xor(pmax, 32));
                if (__any(pmax > m_r[qt] + 11.5415603f)) {
                    float mnew = fmaxf(m_r[qt], pmax);
                    float alpha = fexp2(m_r[qt] - mnew);
                    m_r[qt] = mnew;
                    l_r[qt] *= alpha;
                    float arow[4];
                    #pragma unroll
                    for (int r = 0; r < 4; ++r)
                        arow[r] = __shfl(alpha, g4 + r, 16);
                    #pragma unroll
                    for (int nt = 0; nt < 8; ++nt)
                        #pragma unroll
                        for (int r = 0; r < 4; ++r)
                            o_acc[qt][nt][r] *= arow[r];
                }
                float ps = 0.f;
                #pragma unroll
                for (int jt = 0; jt < 4; ++jt)
                    #pragma unroll
                    for (int r = 0; r < 4; ++r) {
                        float e = fexp2(sacc[qt][jt][r] - m_r[qt]);
                        sacc[qt][jt][r] = e;
                        ps += e;
                    }
                ps += __shfl_xor(ps, 16);
                ps += __shfl_xor(ps, 32);
                l_r[qt] += ps;
                const int prow = (wid * 32 + qt * 16 + l15) * LDP;
                #pragma unroll
                for (int jt = 0; jt < 4; ++jt) {
                    u16x4 w;
                    #pragma unroll
                    for (int r = 0; r < 4; ++r) w[r] = f2bf(sacc[qt][jt][r]);
                    *(u16x4*)&p_lds[prow + jt * 16 + g4] = w;
                }
            }

            u16x8 pf[2][2];
            #pragma unroll
            for (int qt = 0; qt < 2; ++qt)
                #pragma unroll
                for (int ks = 0; ks < 2; ++ks)
                    pf[qt][ks] = *(u16x8*)&p_lds[(wid * 32 + qt * 16 + l15) * LDP +
                                                 ks * 32 + koff];
            #pragma unroll
            for (int nt = 0; nt < 8; ++nt)
                #pragma unroll
                for (int ks = 0; ks < 2; ++ks) {
                    u16x8 vf = *(u16x8*)&v_lds[(nt * 16 + l15) * LDV + ks * 32 + koff];
                    #pragma unroll
                    for (int qt = 0; qt < 2; ++qt)
                        o_acc[qt][nt] = MFMA16(pf[qt][ks], vf, o_acc[qt][nt]);
                }
        }
    }

    #pragma unroll
    for (int qt = 0; qt < 2; ++qt) {
        float lrow[4];
        #pragma unroll
        for (int r = 0; r < 4; ++r)
            lrow[r] = __shfl(l_r[qt], g4 + r, 16);
        #pragma unroll
        for (int r = 0; r < 4; ++r) {
            float inv_l = 1.0f / lrow[r];
            int row = qw + qt * 16 + g4 + r;
            const int r7s = (row & 7) << 3;
            #pragma unroll
            for (int nt = 0; nt < 8; ++nt) {
                int col = h * 128 + nt * 16 + l15;
                O[(size_t)row * 4096 + (col ^ r7s)] =
                    f2bf(o_acc[qt][nt][r] * inv_l);
            }
        }
    }
}

// ---------------------------------------------------------------------------
extern "C" void kernel_launch(void* const* d_in, const int* in_sizes, int n_in,
                              void* d_out, int out_size, void* d_ws, size_t ws_size,
                              hipStream_t stream)
{
    (void)in_sizes; (void)n_in; (void)out_size; (void)ws_size;
    const float* hidden = (const float*)d_in[0];
    const float* wq     = (const float*)d_in[1];
    const float* wk     = (const float*)d_in[2];
    const float* wv     = (const float*)d_in[3];
    const float* wo     = (const float*)d_in[4];
    const float* qnw    = (const float*)d_in[5];
    const float* knw    = (const float*)d_in[6];
    const int*   pos    = (const int*)d_in[8];
    float* out = (float*)d_out;

    const size_t MB = 1024 * 1024;
    char* ws = (char*)d_ws;
    unsigned short* q_ws  = (unsigned short*)(ws);             // 16 MB  [2048][4096]
    unsigned short* k_ws  = (unsigned short*)(ws + 16 * MB);   //  4 MB  [2048][1024]
    unsigned short* vt_ws = (unsigned short*)(ws + 20 * MB);   //  4 MB  [1024][2048]
    unsigned short* hb    = (unsigned short*)(ws + 24 * MB);   // 16 MB  hidden bf16 (swz)
    unsigned short* a_ws  = hb;                                // reuse: attn out (swz)
    unsigned short* wqt   = (unsigned short*)(ws + 40 * MB);   // 32 MB  [4096][4096] swz
    float*          kvP   = (float*)(ws + 40 * MB);            // 32 MB  KV partials (after Q-GEMM)
    unsigned short* wkt   = (unsigned short*)(ws + 72 * MB);   //  8 MB  [1024][4096] swz (+wvt adjacent)
    unsigned short* wot   = (unsigned short*)(ws + 88 * MB);   // 32 MB  [4096][4096] swz

    // merged prep: convert + 4 weight transposes (128x128 tiles) in one dispatch
    prep_all<<<6656, 256, 0, stream>>>(hidden, wq, wk, wv, wo,
                                       hb, wqt, wkt, wot);

    // Q projection (consumes wqt)
    gemm8<unsigned short, 0><<<dim3(16, 16), 512, 0, stream>>>(
        hb, wqt, q_ws, 2048, 4096, 4096);
    // KV projection: K-split x2 into f32 partials (reuses wqt region), combine
    gemm8<float, 3><<<dim3(8, 16, 2), 512, 0, stream>>>(
        hb, wkt, kvP, 2048, 2048, 4096);
    combine_kv<<<dim3(32, 32), 256, 0, stream>>>(kvP, k_ws, vt_ws);

    // merged RoPE+RMSNorm (Q scale = 1/sqrt(128) * log2(e), exp2-domain)
    rope_all<<<2560, 256, 0, stream>>>(q_ws, k_ws, pos, qnw, knw,
                                       0.12751743341633942f);

    attn_kernel<<<512, 256, 0, stream>>>(q_ws, k_ws, vt_ws, a_ws);

    gemm8<float, 0><<<dim3(16, 16), 512, 0, stream>>>(
        a_ws, wot, out, 2048, 4096, 4096);
}

// Round 18
// 326.695 us; speedup vs baseline: 1.1348x; 1.0025x over previous
//
#include <hip/hip_runtime.h>

typedef __bf16 bf16x8 __attribute__((ext_vector_type(8)));
typedef float f32x4 __attribute__((ext_vector_type(4)));
typedef unsigned short u16x8 __attribute__((ext_vector_type(8)));
typedef unsigned short u16x4 __attribute__((ext_vector_type(4)));
typedef unsigned short u16x2 __attribute__((ext_vector_type(2)));

__device__ inline unsigned short f2bf(float f) {
    return __builtin_bit_cast(unsigned short, (__bf16)f);
}
__device__ inline float bf2f(unsigned short u) {
    return (float)__builtin_bit_cast(__bf16, u);
}

// native 2^x (v_exp_f32 is exp2 on gfx950); avoids libm header clash
__device__ __forceinline__ float fexp2(float x) {
    float r;
    asm("v_exp_f32 %0, %1" : "=v"(r) : "v"(x));
    return r;
}

__device__ inline void storeC(float v, float* p) { *p = v; }
__device__ inline void storeC(float v, unsigned short* p) { *p = f2bf(v); }

#define MFMA16(a, b, c) __builtin_amdgcn_mfma_f32_16x16x32_bf16( \
    __builtin_bit_cast(bf16x8, a), __builtin_bit_cast(bf16x8, b), (c), 0, 0, 0)

// async global->LDS, 16B per lane; LDS dest = wave-uniform base + lane*16
__device__ inline void gload16(const unsigned short* g, unsigned short* l) {
    __builtin_amdgcn_global_load_lds(
        (const __attribute__((address_space(1))) unsigned int*)(g),
        (__attribute__((address_space(3))) unsigned int*)(l), 16, 0, 0);
}

__device__ __forceinline__ void bar() {
    asm volatile("" ::: "memory");
    __builtin_amdgcn_s_barrier();
    asm volatile("" ::: "memory");
}
#define WAITVM(N) asm volatile("s_waitcnt vmcnt(" #N ")" ::: "memory")

// ---------------------------------------------------------------------------
// Merged prep: convert + 4 weight transposes, one dispatch.
// 128x128 transpose tiles. Store phase remapped so ONE wave writes 256 B
// contiguous per output row (was 64 B/row/wave in R15 -> poor DRAM write
// segmentation): kc = (lane&15)*8 covers all 16 k-groups in-wave,
// n = p*16 + wave*4 + (lane>>4) gives 4 consecutive rows per wave.
// LDS index has ramp pad (k>>3)*2 so the stride-8-k-row gather hits
// dword step 521 === 9 (mod 32) -> <=2-way banks (free). Output swizzle
// contract unchanged: within each 64-hw k-block, 8-slot ^= (n&7).
// ---------------------------------------------------------------------------
#define LDSIDX(k, n) ((k) * 130 + ((k) >> 3) * 2 + (n))

__device__ void transpose_tile128(const float* __restrict__ W,
                                  unsigned short* __restrict__ WT,
                                  int K, int N, int bx, int by,
                                  unsigned short* t_lds)
{
    const int kt = bx * 128, nt = by * 128;
    const int tid = threadIdx.x;
    // load: 16 passes x 8 rows; row r = 128 floats (512B), 32 thr/row
    const int c = (tid & 31) * 4;
    const int r0 = tid >> 5;
    #pragma unroll
    for (int p = 0; p < 16; ++p) {
        const int r = p * 8 + r0;
        float4 v = *(const float4*)&W[(size_t)(kt + r) * N + nt + c];
        u16x4 h;
        h[0] = f2bf(v.x); h[1] = f2bf(v.y); h[2] = f2bf(v.z); h[3] = f2bf(v.w);
        *(u16x4*)&t_lds[LDSIDX(r, c)] = h;
    }
    __syncthreads();
    // store: 8 passes; wave-contiguous rows: kc=(lane&15)*8, wave w owns
    // rows p*16 + w*4 + (lane>>4) -> 4 rows x 256 B contiguous per wave instr
    const int lane = tid & 63, w = tid >> 6;
    const int kc = (lane & 15) * 8;
    const int nw = w * 4 + (lane >> 4);
    #pragma unroll
    for (int p = 0; p < 8; ++p) {
        const int n = p * 16 + nw;
        u16x8 o;
        #pragma unroll
        for (int j = 0; j < 8; ++j)
            o[j] = t_lds[LDSIDX(kc + j, n)];
        const int swz = (kc & 64) | ((kc & 63) ^ ((n & 7) << 3));
        *(u16x8*)&WT[(size_t)(nt + n) * K + kt + swz] = o;
    }
}

__global__ __launch_bounds__(256) void prep_all(
    const float* __restrict__ hidden, const float* __restrict__ wq,
    const float* __restrict__ wk, const float* __restrict__ wv,
    const float* __restrict__ wo, unsigned short* __restrict__ hb,
    unsigned short* __restrict__ wqt, unsigned short* __restrict__ wkt,
    unsigned short* __restrict__ wot)
{
    __shared__ __attribute__((aligned(16))) unsigned short t_lds[128 * 130 + 32];
    const int bid = blockIdx.x;
    if (bid < 4096) {
        const size_t i = ((size_t)bid * 256 + threadIdx.x) * 8;
        const size_t row7 = (i >> 12) & 7;
        float4 v0 = *(const float4*)&hidden[i];
        float4 v1 = *(const float4*)&hidden[i + 4];
        u16x8 o;
        o[0] = f2bf(v0.x); o[1] = f2bf(v0.y); o[2] = f2bf(v0.z); o[3] = f2bf(v0.w);
        o[4] = f2bf(v1.x); o[5] = f2bf(v1.y); o[6] = f2bf(v1.z); o[7] = f2bf(v1.w);
        *(u16x8*)&hb[i ^ (row7 << 3)] = o;
    } else if (bid < 5120) {
        const int tb = bid - 4096;
        transpose_tile128(wq, wqt, 4096, 4096, tb & 31, tb >> 5, t_lds);
    } else if (bid < 5376) {
        const int tb = bid - 5120;
        transpose_tile128(wk, wkt, 4096, 1024, tb & 31, tb >> 5, t_lds);
    } else if (bid < 5632) {
        const int tb = bid - 5376;
        transpose_tile128(wv, wkt + (size_t)1024 * 4096, 4096, 1024,
                          tb & 31, tb >> 5, t_lds);
    } else {
        const int tb = bid - 5632;
        transpose_tile128(wo, wot, 4096, 4096, tb & 31, tb >> 5, t_lds);
    }
}

// ---------------------------------------------------------------------------
// Phase-interleaved GEMM (R11-exact, best measured): C[M,N] = A[M,K] * B^T,
// A/B bf16 K-major, sources pre-swizzled. 128x256 tile, BK=64, 8 waves
// (2Mx4N of 64x64), TRIPLE-buffered LDS, 2 phases + 3 barriers per K-tile,
// counted vmcnt(6) once per tile.
// CMODE 0: full K, C[M][N].
// CMODE 3: K-split over blockIdx.z (each z does 2048 of K), raw f32 tile
//          stored to C + z*M*N (partials; combined by combine_kv).
// ---------------------------------------------------------------------------
template <typename CT, int CMODE>
__global__ __launch_bounds__(512) void gemm8(
    const unsigned short* __restrict__ A, const unsigned short* __restrict__ B,
    CT* __restrict__ C, int M, int N, int K)
{
    constexpr int ASZ = 128 * 64, BSZ = 256 * 64;
    __shared__ __attribute__((aligned(16))) unsigned short a_lds[3 * ASZ];
    __shared__ __attribute__((aligned(16))) unsigned short b_lds[3 * BSZ];

    const int bm0 = blockIdx.y * 128, bn0 = blockIdx.x * 256;
    const int tid = threadIdx.x, lane = tid & 63, wid = tid >> 6;
    const int wr = wid >> 2, wc = wid & 3;
    const int l15 = lane & 15, koff = (lane >> 4) * 8;
    const int sw = (l15 & 7) << 3;
    const int cb0 = koff ^ sw;
    const int cb1 = (32 + koff) ^ sw;

    f32x4 acc[4][4] = {};

    const size_t kbase = (CMODE == 3) ? (size_t)blockIdx.z * 2048 : 0;

    const unsigned short* ag[2];
    const unsigned short* bg[4];
    #pragma unroll
    for (int p = 0; p < 2; ++p) {
        const int row = (wid + p * 8) * 8 + (lane >> 3);
        ag[p] = A + (size_t)(bm0 + row) * K + (lane & 7) * 8 + kbase;
    }
    #pragma unroll
    for (int p = 0; p < 4; ++p) {
        const int row = (wid + p * 8) * 8 + (lane >> 3);
        bg[p] = B + (size_t)(bn0 + row) * K + (lane & 7) * 8 + kbase;
    }

    const int nt = (CMODE == 3) ? 32 : (K >> 6);

    auto stageA = [&](int s, int kt, int p) {
        gload16(ag[p] + kt, a_lds + s * ASZ + (wid + p * 8) * 512);
    };
    auto stageB = [&](int s, int kt, int p) {
        gload16(bg[p] + kt, b_lds + s * BSZ + (wid + p * 8) * 512);
    };

    #pragma unroll
    for (int p = 0; p < 2; ++p) stageA(0, 0, p);
    #pragma unroll
    for (int p = 0; p < 4; ++p) stageB(0, 0, p);
    #pragma unroll
    for (int p = 0; p < 2; ++p) stageA(1, 64, p);
    #pragma unroll
    for (int p = 0; p < 4; ++p) stageB(1, 64, p);
    WAITVM(6);
    bar();

    int sc = 0;
    for (int t = 0; t < nt; ++t) {
        const unsigned short* ab = a_lds + sc * ASZ;
        const unsigned short* bb = b_lds + sc * BSZ;
        const int ss = (sc >= 1) ? sc - 1 : 2;
        const int kt2 = (t + 2) << 6;
        const bool st = (t + 2) < nt;

        u16x8 af0, af1, af2, af3, bfr[4];

        // ---- Phase A: kk0 reads + 3 gloads, then 16 MFMA
        af0 = *(const u16x8*)&ab[(wr * 64 + 0 * 16 + l15) * 64 + cb0];
        af1 = *(const u16x8*)&ab[(wr * 64 + 1 * 16 + l15) * 64 + cb0];
        af2 = *(const u16x8*)&ab[(wr * 64 + 2 * 16 + l15) * 64 + cb0];
        af3 = *(const u16x8*)&ab[(wr * 64 + 3 * 16 + l15) * 64 + cb0];
        #pragma unroll
        for (int j = 0; j < 4; ++j)
            bfr[j] = *(const u16x8*)&bb[(wc * 64 + j * 16 + l15) * 64 + cb0];
        if (st) { stageA(ss, kt2, 0); stageA(ss, kt2, 1); stageB(ss, kt2, 0); }
        bar();
        __builtin_amdgcn_s_setprio(1);
        #pragma unroll
        for (int j = 0; j < 4; ++j) {
            acc[0][j] = MFMA16(af0, bfr[j], acc[0][j]);
            acc[1][j] = MFMA16(af1, bfr[j], acc[1][j]);
            acc[2][j] = MFMA16(af2, bfr[j], acc[2][j]);
            acc[3][j] = MFMA16(af3, bfr[j], acc[3][j]);
        }
        __builtin_amdgcn_s_setprio(0);

        // ---- Phase B: kk1 reads + 3 gloads + counted vmcnt, then 16 MFMA
        af0 = *(const u16x8*)&ab[(wr * 64 + 0 * 16 + l15) * 64 + cb1];
        af1 = *(const u16x8*)&ab[(wr * 64 + 1 * 16 + l15) * 64 + cb1];
        af2 = *(const u16x8*)&ab[(wr * 64 + 2 * 16 + l15) * 64 + cb1];
        af3 = *(const u16x8*)&ab[(wr * 64 + 3 * 16 + l15) * 64 + cb1];
        #pragma unroll
        for (int j = 0; j < 4; ++j)
            bfr[j] = *(const u16x8*)&bb[(wc * 64 + j * 16 + l15) * 64 + cb1];
        if (st) {
            stageB(ss, kt2, 1); stageB(ss, kt2, 2); stageB(ss, kt2, 3);
            WAITVM(6);
        } else {
            WAITVM(0);
        }
        bar();
        __builtin_amdgcn_s_setprio(1);
        #pragma unroll
        for (int j = 0; j < 4; ++j) {
            acc[0][j] = MFMA16(af0, bfr[j], acc[0][j]);
            acc[1][j] = MFMA16(af1, bfr[j], acc[1][j]);
            acc[2][j] = MFMA16(af2, bfr[j], acc[2][j]);
            acc[3][j] = MFMA16(af3, bfr[j], acc[3][j]);
        }
        __builtin_amdgcn_s_setprio(0);

        bar();              // tile end: all reads of slot sc complete
        sc = (sc == 2) ? 0 : sc + 1;
    }

    CT* Cb = C;
    if constexpr (CMODE == 3)
        Cb = C + (size_t)blockIdx.z * M * N;

    #pragma unroll
    for (int i = 0; i < 4; ++i)
        #pragma unroll
        for (int r = 0; r < 4; ++r) {
            const int row = bm0 + wr * 64 + i * 16 + (lane >> 4) * 4 + r;
            size_t base = (size_t)row * N + bn0 + wc * 64 + l15;
            #pragma unroll
            for (int j = 0; j < 4; ++j)
                storeC(acc[i][j][r], &Cb[base + j * 16]);
        }
}

// ---------------------------------------------------------------------------
// combine_kv: P0+P1 (f32 [2][2048][2048] K-split partials) ->
//   cols <1024  : k_ws bf16 [2048][1024] (direct)
//   cols >=1024 : vt_ws bf16 [1024][2048] (transposed via LDS)
// ---------------------------------------------------------------------------
__global__ __launch_bounds__(256) void combine_kv(
    const float* __restrict__ P, unsigned short* __restrict__ Kout,
    unsigned short* __restrict__ VTout)
{
    const float* P0 = P;
    const float* P1 = P + (size_t)2048 * 2048;
    const int s0 = blockIdx.y * 64, c0 = blockIdx.x * 64;
    const int tid = threadIdx.x;
    const int row = tid >> 2;
    const int cbl = (tid & 3) * 16;
    const size_t gbase = (size_t)(s0 + row) * 2048 + c0 + cbl;
    u16x8 o[2];
    #pragma unroll
    for (int j = 0; j < 2; ++j) {
        float4 a0 = *(const float4*)&P0[gbase + j * 8];
        float4 b0 = *(const float4*)&P1[gbase + j * 8];
        float4 a1 = *(const float4*)&P0[gbase + j * 8 + 4];
        float4 b1 = *(const float4*)&P1[gbase + j * 8 + 4];
        o[j][0] = f2bf(a0.x + b0.x); o[j][1] = f2bf(a0.y + b0.y);
        o[j][2] = f2bf(a0.z + b0.z); o[j][3] = f2bf(a0.w + b0.w);
        o[j][4] = f2bf(a1.x + b1.x); o[j][5] = f2bf(a1.y + b1.y);
        o[j][6] = f2bf(a1.z + b1.z); o[j][7] = f2bf(a1.w + b1.w);
    }
    if (c0 < 1024) {
        #pragma unroll
        for (int j = 0; j < 2; ++j)
            *(u16x8*)&Kout[(size_t)(s0 + row) * 1024 + c0 + cbl + j * 8] = o[j];
    } else {
        constexpr int LDT = 66;
        __shared__ unsigned short t_lds[64 * LDT];
        #pragma unroll
        for (int j = 0; j < 2; ++j)
            *(u16x8*)&t_lds[row * LDT + cbl + j * 8] = o[j];
        __syncthreads();
        const int d = row;
        #pragma unroll
        for (int j = 0; j < 2; ++j) {
            u16x8 w;
            #pragma unroll
            for (int e = 0; e < 8; ++e)
                w[e] = t_lds[(cbl + j * 8 + e) * LDT + d];
            *(u16x8*)&VTout[(size_t)(c0 - 1024 + d) * 2048 + s0 + cbl + j * 8] = w;
        }
    }
}

// ---------------------------------------------------------------------------
// Merged RoPE + RMSNorm (Q and K in one dispatch), in-place on bf16.
//   bid [0,2048)    : Q row s=bid, H=32 (256 threads, 8 per head)
//   bid [2048,2560) : K rows s=(bid-2048)*4 + (tid>>6), H=8 (64 thr/row)
// ---------------------------------------------------------------------------
__device__ void rope_row(unsigned short* __restrict__ X,
                         const float* __restrict__ W,
                         float fpos, int rowstride, size_t s, int h, int t8,
                         float outscale)
{
    unsigned short* p = X + s * rowstride + h * 128 + t8 * 8;
    u16x8 lo = *(u16x8*)p;
    u16x8 hi = *(u16x8*)(p + 64);
    float na[8], nb[8];
    float ss = 0.f;
    #pragma unroll
    for (int j = 0; j < 8; ++j) {
        const int d = t8 * 8 + j;
        float inv = expf(-0.14391156831212787f * (float)d);
        float fr = fpos * inv;
        float c = cosf(fr), sn = sinf(fr);
        float a = bf2f(lo[j]), b = bf2f(hi[j]);
        na[j] = a * c - b * sn;
        nb[j] = b * c + a * sn;
        ss += na[j] * na[j] + nb[j] * nb[j];
    }
    ss += __shfl_xor(ss, 1, 8);
    ss += __shfl_xor(ss, 2, 8);
    ss += __shfl_xor(ss, 4, 8);
    const float rn = rsqrtf(ss * (1.0f / 128.0f) + 1e-6f) * outscale;
    #pragma unroll
    for (int j = 0; j < 8; ++j) {
        const int d = t8 * 8 + j;
        lo[j] = f2bf(na[j] * rn * W[d]);
        hi[j] = f2bf(nb[j] * rn * W[d + 64]);
    }
    *(u16x8*)p = lo;
    *(u16x8*)(p + 64) = hi;
}

__global__ void rope_all(unsigned short* __restrict__ Q,
                         unsigned short* __restrict__ K,
                         const int* __restrict__ pos_ids,
                         const float* __restrict__ qw,
                         const float* __restrict__ kw,
                         float qscale)
{
    const int bid = blockIdx.x;
    const int tid = threadIdx.x;
    if (bid < 2048) {
        rope_row(Q, qw, (float)pos_ids[bid], 4096, (size_t)bid,
                 tid >> 3, tid & 7, qscale);
    } else {
        const size_t s = (size_t)(bid - 2048) * 4 + (tid >> 6);
        rope_row(K, kw, (float)pos_ids[s], 1024, s,
                 (tid & 63) >> 3, tid & 7, 1.0f);
    }
}

// ---------------------------------------------------------------------------
// Causal flash attention (R11-proven), V^T input, bf16 swizzled output.
// Swapped QK^T (mfma(K,Q) -> S^T): softmax is lane-local (q = lane&15),
// row-reduce = 2 shfls. Defer-rescale. Packed b64 P-writes. exp2-domain
// softmax (log2e folded into Q scale); fexp2 = native v_exp_f32.
// Grid: bid&7 = kv-head (XCD L2 affinity), heavy q-blocks first.
// ---------------------------------------------------------------------------
__global__ __launch_bounds__(256, 2) void attn_kernel(
    const unsigned short* __restrict__ Q, const unsigned short* __restrict__ K,
    const unsigned short* __restrict__ VT, unsigned short* __restrict__ O)
{
    constexpr int LDK = 136, LDV = 72, LDP = 72;
    __shared__ __attribute__((aligned(16))) unsigned short k_lds[64 * LDK];
    __shared__ __attribute__((aligned(16))) unsigned short v_lds[128 * LDV];
    __shared__ __attribute__((aligned(16))) unsigned short p_lds[4 * 32 * LDP];

    const int bid = blockIdx.x;
    const int kvh = bid & 7;
    const int rest = bid >> 3;
    const int h = kvh * 4 + (rest & 3);
    const int qb = 15 - (rest >> 2);
    const int q0 = qb * 128;
    const int tid = threadIdx.x, lane = tid & 63, wid = tid >> 6;
    const int l15 = lane & 15, g4 = (lane >> 4) * 4, koff = (lane >> 4) * 8;
    const int qw = q0 + wid * 32;

    u16x8 qf[2][4];
    #pragma unroll
    for (int qt = 0; qt < 2; ++qt)
        #pragma unroll
        for (int kk = 0; kk < 4; ++kk)
            qf[qt][kk] = *(const u16x8*)&Q[(size_t)(qw + qt * 16 + l15) * 4096 +
                                           h * 128 + kk * 32 + koff];

    f32x4 o_acc[2][8] = {};
    float m_r[2] = {-1e30f, -1e30f}, l_r[2] = {0.f, 0.f};

    const int kr = tid >> 2, kd = (tid & 3) * 32;
    const int vr = tid >> 1, vc = (tid & 1) * 32;
    const unsigned short* kg = K + (size_t)kvh * 128 + kd;
    const unsigned short* vg = VT + (size_t)(kvh * 128 + vr) * 2048 + vc;

    const int nchunk = qb * 2 + 2;
    u16x8 kst[4], vst[4];
    #pragma unroll
    for (int j = 0; j < 4; ++j) {
        kst[j] = *(const u16x8*)&kg[(size_t)kr * 1024 + j * 8];
        vst[j] = *(const u16x8*)&vg[j * 8];
    }

    for (int ch = 0; ch < nchunk; ++ch) {
        const int kv0 = ch * 64;
        __syncthreads();
        #pragma unroll
        for (int j = 0; j < 4; ++j) {
            *(u16x8*)&k_lds[kr * LDK + kd + j * 8] = kst[j];
            *(u16x8*)&v_lds[vr * LDV + vc + j * 8] = vst[j];
        }
        __syncthreads();
        if (ch + 1 < nchunk) {
            const int kv1 = kv0 + 64;
            #pragma unroll
            for (int j = 0; j < 4; ++j) {
                kst[j] = *(const u16x8*)&kg[(size_t)(kv1 + kr) * 1024 + j * 8];
                vst[j] = *(const u16x8*)&vg[kv1 + j * 8];
            }
        }

        if (kv0 <= qw + 31) {
            f32x4 sacc[2][4] = {};
            #pragma unroll
            for (int kk = 0; kk < 4; ++kk)
                #pragma unroll
                for (int jt = 0; jt < 4; ++jt) {
                    u16x8 kf = *(u16x8*)&k_lds[(jt * 16 + l15) * LDK + kk * 32 + koff];
                    #pragma unroll
                    for (int qt = 0; qt < 2; ++qt)
                        sacc[qt][jt] = MFMA16(kf, qf[qt][kk], sacc[qt][jt]);
                }

            const bool needmask = (kv0 + 63 > qw);
            #pragma unroll
            for (int qt = 0; qt < 2; ++qt) {
                const int q = qw + qt * 16 + l15;
                if (needmask) {
                    #pragma unroll
                    for (int jt = 0; jt < 4; ++jt)
                        #pragma unroll
                        for (int r = 0; r < 4; ++r)
                            if (kv0 + jt * 16 + g4 + r > q) sacc[qt][jt][r] = -1e9f;
                }
                float pmax = sacc[qt][0][0];
                #pragma unroll
                for (int jt = 0; jt < 4; ++jt)
                    #pragma unroll
                    for (int r = 0; r < 4; ++r)
                        pmax = fmaxf(pmax, sacc[qt][jt][r]);
                pmax = fmaxf(pmax, __shfl_xor(pmax, 16));
                pmax = fmaxf(pmax, __shfl_xor(pmax, 32));
                if (__any(pmax > m_r[qt] + 11.5415603f)) {
                    float mnew = fmaxf(m_r[qt], pmax);
                    float alpha = fexp2(m_r[qt] - mnew);
                    m_r[qt] = mnew;
                    l_r[qt] *= alpha;
                    float arow[4];
                    #pragma unroll
                    for (int r = 0; r < 4; ++r)
                        arow[r] = __shfl(alpha, g4 + r, 16);
                    #pragma unroll
                    for (int nt = 0; nt < 8; ++nt)
                        #pragma unroll
                        for (int r = 0; r < 4; ++r)
                            o_acc[qt][nt][r] *= arow[r];
                }
                float ps = 0.f;
                #pragma unroll
                for (int jt = 0; jt < 4; ++jt)
                    #pragma unroll
                    for (int r = 0; r < 4; ++r) {
                        float e = fexp2(sacc[qt][jt][r] - m_r[qt]);
                        sacc[qt][jt][r] = e;
                        ps += e;
                    }
                ps += __shfl_xor(ps, 16);
                ps += __shfl_xor(ps, 32);
                l_r[qt] += ps;
                const int prow = (wid * 32 + qt * 16 + l15) * LDP;
                #pragma unroll
                for (int jt = 0; jt < 4; ++jt) {
                    u16x4 w;
                    #pragma unroll
                    for (int r = 0; r < 4; ++r) w[r] = f2bf(sacc[qt][jt][r]);
                    *(u16x4*)&p_lds[prow + jt * 16 + g4] = w;
                }
            }

            u16x8 pf[2][2];
            #pragma unroll
            for (int qt = 0; qt < 2; ++qt)
                #pragma unroll
                for (int ks = 0; ks < 2; ++ks)
                    pf[qt][ks] = *(u16x8*)&p_lds[(wid * 32 + qt * 16 + l15) * LDP +
                                                 ks * 32 + koff];
            #pragma unroll
            for (int nt = 0; nt < 8; ++nt)
                #pragma unroll
                for (int ks = 0; ks < 2; ++ks) {
                    u16x8 vf = *(u16x8*)&v_lds[(nt * 16 + l15) * LDV + ks * 32 + koff];
                    #pragma unroll
                    for (int qt = 0; qt < 2; ++qt)
                        o_acc[qt][nt] = MFMA16(pf[qt][ks], vf, o_acc[qt][nt]);
                }
        }
    }

    #pragma unroll
    for (int qt = 0; qt < 2; ++qt) {
        float lrow[4];
        #pragma unroll
        for (int r = 0; r < 4; ++r)
            lrow[r] = __shfl(l_r[qt], g4 + r, 16);
        #pragma unroll
        for (int r = 0; r < 4; ++r) {
            float inv_l = 1.0f / lrow[r];
            int row = qw + qt * 16 + g4 + r;
            const int r7s = (row & 7) << 3;
            #pragma unroll
            for (int nt = 0; nt < 8; ++nt) {
                int col = h * 128 + nt * 16 + l15;
                O[(size_t)row * 4096 + (col ^ r7s)] =
                    f2bf(o_acc[qt][nt][r] * inv_l);
            }
        }
    }
}

// ---------------------------------------------------------------------------
extern "C" void kernel_launch(void* const* d_in, const int* in_sizes, int n_in,
                              void* d_out, int out_size, void* d_ws, size_t ws_size,
                              hipStream_t stream)
{
    (void)in_sizes; (void)n_in; (void)out_size; (void)ws_size;
    const float* hidden = (const float*)d_in[0];
    const float* wq     = (const float*)d_in[1];
    const float* wk     = (const float*)d_in[2];
    const float* wv     = (const float*)d_in[3];
    const float* wo     = (const float*)d_in[4];
    const float* qnw    = (const float*)d_in[5];
    const float* knw    = (const float*)d_in[6];
    const int*   pos    = (const int*)d_in[8];
    float* out = (float*)d_out;

    const size_t MB = 1024 * 1024;
    char* ws = (char*)d_ws;
    unsigned short* q_ws  = (unsigned short*)(ws);             // 16 MB  [2048][4096]
    unsigned short* k_ws  = (unsigned short*)(ws + 16 * MB);   //  4 MB  [2048][1024]
    unsigned short* vt_ws = (unsigned short*)(ws + 20 * MB);   //  4 MB  [1024][2048]
    unsigned short* hb    = (unsigned short*)(ws + 24 * MB);   // 16 MB  hidden bf16 (swz)
    unsigned short* a_ws  = hb;                                // reuse: attn out (swz)
    unsigned short* wqt   = (unsigned short*)(ws + 40 * MB);   // 32 MB  [4096][4096] swz
    float*          kvP   = (float*)(ws + 40 * MB);            // 32 MB  KV partials (after Q-GEMM)
    unsigned short* wkt   = (unsigned short*)(ws + 72 * MB);   //  8 MB  [1024][4096] swz (+wvt adjacent)
    unsigned short* wot   = (unsigned short*)(ws + 88 * MB);   // 32 MB  [4096][4096] swz

    // merged prep: convert + 4 weight transposes (128x128 tiles) in one dispatch
    prep_all<<<6656, 256, 0, stream>>>(hidden, wq, wk, wv, wo,
                                       hb, wqt, wkt, wot);

    // Q projection (consumes wqt)
    gemm8<unsigned short, 0><<<dim3(16, 16), 512, 0, stream>>>(
        hb, wqt, q_ws, 2048, 4096, 4096);
    // KV projection: K-split x2 into f32 partials (reuses wqt region), combine
    gemm8<float, 3><<<dim3(8, 16, 2), 512, 0, stream>>>(
        hb, wkt, kvP, 2048, 2048, 4096);
    combine_kv<<<dim3(32, 32), 256, 0, stream>>>(kvP, k_ws, vt_ws);

    // merged RoPE+RMSNorm (Q scale = 1/sqrt(128) * log2(e), exp2-domain)
    rope_all<<<2560, 256, 0, stream>>>(q_ws, k_ws, pos, qnw, knw,
                                       0.12751743341633942f);

    attn_kernel<<<512, 256, 0, stream>>>(q_ws, k_ws, vt_ws, a_ws);

    gemm8<float, 0><<<dim3(16, 16), 512, 0, stream>>>(
        a_ws, wot, out, 2048, 4096, 4096);
}